// Round 1
// baseline (121.135 us; speedup 1.0000x reference)
//
#include <hip/hip_runtime.h>
#include <math.h>

namespace {

constexpr int kS = 26;
constexpr int kA = 5;
constexpr int kP = kS * kS * kA;        // 3380
constexpr int kM = 30;
constexpr int kB = 128;
constexpr float kCW = 16.0f;            // IM / S = 416 / 26
constexpr int kThreads = 512;
constexpr int kWaves = kThreads / 64;   // 8
constexpr int kMaskW = (kP + 31) / 32;  // 106

__device__ __forceinline__ float sig(float x) { return 1.0f / (1.0f + expf(-x)); }

__global__ __launch_bounds__(kThreads) void loss_main(
    const float* __restrict__ pred,
    const float* __restrict__ targ,
    const float* __restrict__ anch,
    float* __restrict__ ws) {
  __shared__ float4 sbox[kP];            // decoded (bx,by,bw,bh), 54 KB
  __shared__ unsigned int sobj[kMaskW];  // obj bitmask over P
  __shared__ float t_raw[kM * 5];
  __shared__ float g_x1[kM], g_x2[kM], g_y1[kM], g_y2[kM], g_area[kM];
  __shared__ int s_valid[kM];
  __shared__ int s_idx[kM];
  __shared__ float s_anc[2 * kA];
  __shared__ float red[kWaves][3];

  const int b = blockIdx.x;
  const int tid = threadIdx.x;
  const int lane = tid & 63;
  const int wid = tid >> 6;

  if (tid < 2 * kA) s_anc[tid] = anch[tid];
  if (tid < kM * 5) t_raw[tid] = targ[b * (kM * 5) + tid];
  for (int i = tid; i < kMaskW; i += kThreads) sobj[i] = 0u;
  __syncthreads();

  if (tid < kM) {
    const float t0 = t_raw[tid * 5 + 0];
    const float t1 = t_raw[tid * 5 + 1];
    const float t2 = t_raw[tid * 5 + 2];
    const float t3 = t_raw[tid * 5 + 3];
    const float t4 = t_raw[tid * 5 + 4];
    const float gxc = t0 + t2 * 0.5f;   // t0 + t2/2
    const float gyc = t1 + t3 * 0.5f;
    const float gw = t2 - t0;           // faithful to source
    const float gh = t3 * t1;           // faithful to source
    g_x1[tid] = gxc - gw * 0.5f;
    g_x2[tid] = gxc + gw * 0.5f;
    g_y1[tid] = gyc - gh * 0.5f;
    g_y2[tid] = gyc + gh * 0.5f;
    g_area[tid] = gw * gh;
    s_valid[tid] = (t4 == 1.0f) ? 1 : 0;
  }
  __syncthreads();

  // ---- phase 1: decode boxes into LDS; accumulate sum(conf^2) over all p ----
  float c2_all = 0.0f;
  for (int p = tid; p < kP; p += kThreads) {
    const float* pp = pred + (b * kP + p) * 25;
    const float s0 = sig(pp[0]);
    const float s1 = sig(pp[1]);
    const float s2 = sig(pp[2]) * 0.5f;
    const float s3 = sig(pp[3]) * 0.5f;
    const float c = sig(pp[4]);
    c2_all += c * c;
    const int a = p % kA;
    const int gx = (p / kA) % kS;
    const int gy = p / (kA * kS);
    float4 box;
    box.x = (s0 + (float)gx) * kCW;
    box.y = (s1 + (float)gy) * kCW;
    box.z = expf(s2) * s_anc[2 * a + 0] * kCW;
    box.w = expf(s3) * s_anc[2 * a + 1] * kCW;
    sbox[p] = box;
  }
  __syncthreads();

  // ---- phase 2: per-valid-GT argmax over p (first-index tie-break) + obj mask ----
  for (int m = wid; m < kM; m += kWaves) {
    if (!s_valid[m]) continue;  // block-... wave-uniform branch
    const float gx1 = g_x1[m], gx2 = g_x2[m];
    const float gy1 = g_y1[m], gy2 = g_y2[m];
    const float ga = g_area[m];
    float best = -INFINITY;
    int bi = 0;
    for (int p = lane; p < kP; p += 64) {
      const float4 box = sbox[p];
      const float hw = box.z * 0.5f, hh = box.w * 0.5f;
      const float px1 = box.x - hw, px2 = box.x + hw;  // exactly pbox[...,0] -+ pbox[...,2]/2
      const float py1 = box.y - hh, py2 = box.y + hh;
      float dx = fminf(gx2, px2) - fmaxf(gx1, px1);
      float dy = fminf(gy2, py2) - fmaxf(gy1, py1);
      dx = fmaxf(dx, 0.0f);
      dy = fmaxf(dy, 0.0f);
      const float inter = dx * dy;
      const float uni = ga + box.z * box.w - inter;
      const float iou = inter / (uni + 1e-9f);
      if (iou > 0.6f) atomicOr(&sobj[p >> 5], 1u << (p & 31));
      if (iou > best) { best = iou; bi = p; }  // strict > keeps first occurrence
    }
#pragma unroll
    for (int off = 32; off > 0; off >>= 1) {
      const float ob = __shfl_down(best, off);
      const int oi = __shfl_down(bi, off);
      if (ob > best || (ob == best && oi < bi)) { best = ob; bi = oi; }
    }
    if (lane == 0) s_idx[m] = bi;
  }
  __syncthreads();

  // ---- phase 3: sparse conf-obj terms ----
  float obj_term = 0.0f, obj_c2 = 0.0f;
  for (int w = tid; w < kMaskW; w += kThreads) {
    unsigned int bits = sobj[w];
    while (bits) {
      const int bit = __ffs(bits) - 1;
      bits &= bits - 1;
      const int p = (w << 5) | bit;
      const float c = sig(pred[(b * kP + p) * 25 + 4]);
      const float d = c - 1.0f;
      obj_term += d * d;
      obj_c2 += c * c;
    }
  }

  // ---- phase 4: loc loss; duplicate scatter indices -> LAST valid m wins ----
  float loc = 0.0f;
  if (tid < kM && s_valid[tid]) {
    const int m = tid;
    const int idx = s_idx[m];
    bool live = true;
    for (int m2 = m + 1; m2 < kM; ++m2) {
      if (s_valid[m2] && s_idx[m2] == idx) { live = false; break; }
    }
    if (live) {
      const float t0 = t_raw[m * 5 + 0];
      const float t1 = t_raw[m * 5 + 1];
      const float t2 = t_raw[m * 5 + 2];
      const float t3 = t_raw[m * 5 + 3];
      const float gxc = t0 + t2 * 0.5f;
      const float gyc = t1 + t3 * 0.5f;
      const int ra = idx % kA;
      const int rw = (idx / kA) % kS;
      const int rh = idx / (kA * kS);
      const float tx = (gxc - (float)rw * kCW) / kCW;
      const float ty = (gyc - (float)rh * kCW) / kCW;
      const float tw = logf((t2 / kCW) / s_anc[2 * ra + 0]);
      const float th = logf((t3 / kCW) / s_anc[2 * ra + 1]);
      const float* pp = pred + (b * kP + idx) * 25;
      const float d0 = sig(pp[0]) - tx;
      const float d1 = sig(pp[1]) - ty;
      const float d2 = sig(pp[2]) * 0.5f - tw;
      const float d3 = sig(pp[3]) * 0.5f - th;
      loc = d0 * d0 + d1 * d1 + d2 * d2 + d3 * d3;
    }
  }

  // ---- block reduce: [obj_term, noobj = c2_all - obj_c2, loc] ----
  float v0 = obj_term;
  float v1 = c2_all - obj_c2;
  float v2 = loc;
#pragma unroll
  for (int off = 32; off > 0; off >>= 1) {
    v0 += __shfl_down(v0, off);
    v1 += __shfl_down(v1, off);
    v2 += __shfl_down(v2, off);
  }
  if (lane == 0) { red[wid][0] = v0; red[wid][1] = v1; red[wid][2] = v2; }
  __syncthreads();
  if (tid == 0) {
    float a0 = 0.f, a1 = 0.f, a2 = 0.f;
    for (int w = 0; w < kWaves; ++w) { a0 += red[w][0]; a1 += red[w][1]; a2 += red[w][2]; }
    ws[b * 3 + 0] = a0;
    ws[b * 3 + 1] = a1;
    ws[b * 3 + 2] = a2;
  }
}

__global__ __launch_bounds__(kB) void loss_final(const float* __restrict__ ws,
                                                 float* __restrict__ out) {
  __shared__ float red[2][3];
  const int tid = threadIdx.x;  // 128 threads = 2 waves
  float a0 = ws[tid * 3 + 0];
  float a1 = ws[tid * 3 + 1];
  float a2 = ws[tid * 3 + 2];
#pragma unroll
  for (int off = 32; off > 0; off >>= 1) {
    a0 += __shfl_down(a0, off);
    a1 += __shfl_down(a1, off);
    a2 += __shfl_down(a2, off);
  }
  if ((tid & 63) == 0) {
    red[tid >> 6][0] = a0;
    red[tid >> 6][1] = a1;
    red[tid >> 6][2] = a2;
  }
  __syncthreads();
  if (tid == 0) {
    const float obj = red[0][0] + red[1][0];
    const float noobj = red[0][1] + red[1][1];
    const float locs = red[0][2] + red[1][2];
    const float loss_conf = (obj + 0.5f * noobj) / (float)kB;
    const float loss_loc = 5.0f * locs / (float)kB;
    out[0] = loss_loc + loss_conf;
    out[1] = loss_loc;
    out[2] = loss_conf;
  }
}

}  // namespace

extern "C" void kernel_launch(void* const* d_in, const int* in_sizes, int n_in,
                              void* d_out, int out_size, void* d_ws, size_t ws_size,
                              hipStream_t stream) {
  const float* pred = (const float*)d_in[0];
  const float* targ = (const float*)d_in[1];
  const float* anch = (const float*)d_in[2];
  float* out = (float*)d_out;
  float* ws = (float*)d_ws;  // 128 * 3 floats of partials
  loss_main<<<kB, kThreads, 0, stream>>>(pred, targ, anch, ws);
  loss_final<<<1, kB, 0, stream>>>(ws, out);
}